// Round 1
// baseline (65.693 us; speedup 1.0000x reference)
//
#include <hip/hip_runtime.h>

// ---------------------------------------------------------------------------
// TT-adapter fused kernel for MI355X (gfx950)
// out = hs + gelu(hs @ W_down + b_down) @ W_up + b_up
// W_down [768,64], W_up [64,768] reconstructed from rank-5 TT cores.
//
// Kernel 0: build bf16 weights in MFMA-fragment-ready layout in d_ws.
// Kernel 1: fused down-GEMM + gelu + up-GEMM + residual, 32 rows/block.
// ---------------------------------------------------------------------------

typedef __attribute__((ext_vector_type(8))) short bf16x8;
typedef __attribute__((ext_vector_type(4))) float f32x4;

__device__ __forceinline__ unsigned short f2bf(float f) {
    union { float f; unsigned u; } v; v.f = f;
    unsigned r = (v.u + 0x7FFFu + ((v.u >> 16) & 1u)) >> 16;
    return (unsigned short)r;
}
__device__ __forceinline__ float bf2f(unsigned short h) {
    union { unsigned u; float f; } v; v.u = ((unsigned)h) << 16;
    return v.f;
}

// Staged TT contraction for one matrix entry. Core base pointers are in LDS.
// c0:[1,8,5] c1:[5,8,5] c2:[5,12,5] c3:[5,8,5] c4:[5,8,1]
__device__ __forceinline__ float tt_entry(
    const float* c0, const float* c1, const float* c2,
    const float* c3, const float* c4,
    int i0, int i1, int i2, int i3, int i4)
{
    float v1[5], v2[5], v3[5];
#pragma unroll
    for (int r2 = 0; r2 < 5; ++r2) {
        float s = 0.f;
#pragma unroll
        for (int r1 = 0; r1 < 5; ++r1)
            s += c0[i0 * 5 + r1] * c1[(r1 * 8 + i1) * 5 + r2];
        v1[r2] = s;
    }
#pragma unroll
    for (int r3 = 0; r3 < 5; ++r3) {
        float s = 0.f;
#pragma unroll
        for (int r2 = 0; r2 < 5; ++r2)
            s += v1[r2] * c2[(r2 * 12 + i2) * 5 + r3];
        v2[r3] = s;
    }
#pragma unroll
    for (int r4 = 0; r4 < 5; ++r4) {
        float s = 0.f;
#pragma unroll
        for (int r3 = 0; r3 < 5; ++r3)
            s += v2[r3] * c3[(r3 * 8 + i3) * 5 + r4];
        v3[r4] = s;
    }
    float w = 0.f;
#pragma unroll
    for (int r4 = 0; r4 < 5; ++r4)
        w += v3[r4] * c4[r4 * 8 + i4];
    return w;
}

// Build WdFrag / WuFrag (bf16) in MFMA-B-fragment layout:
//  WdFrag[((ks*4+nt)*64 + lane)*8 + j] = Wd[ks*32 + (lane>>4)*8 + j][nt*16 + (lane&15)]
//  WuFrag[((s*48+ht)*64 + lane)*8 + j] = Wu[s*32  + (lane>>4)*8 + j][ht*16 + (lane&15)]
// 49152 entries each; grid 384 x 256 covers both.
__global__ __launch_bounds__(256) void tt_build_frags(
    const float* __restrict__ d0, const float* __restrict__ d1,
    const float* __restrict__ d2, const float* __restrict__ d3,
    const float* __restrict__ d4,
    const float* __restrict__ u0, const float* __restrict__ u1,
    const float* __restrict__ u2, const float* __restrict__ u3,
    const float* __restrict__ u4,
    unsigned short* __restrict__ wdFrag, unsigned short* __restrict__ wuFrag)
{
    __shared__ float cs[1560];
    {
        const float* srcs[10] = { d0, d1, d2, d3, d4, u0, u1, u2, u3, u4 };
        const int sizes[10]   = { 40, 200, 300, 200, 40, 40, 200, 300, 200, 40 };
        const int offs[10]    = { 0, 40, 240, 540, 740, 780, 820, 1020, 1320, 1520 };
#pragma unroll
        for (int c = 0; c < 10; ++c)
            for (int i = threadIdx.x; i < sizes[c]; i += 256)
                cs[offs[c] + i] = srcs[c][i];
    }
    __syncthreads();

    int e = blockIdx.x * 256 + threadIdx.x;   // 0..98303
    bool isUp = (e >= 49152);
    int idx = isUp ? (e - 49152) : e;
    int j    = idx & 7;
    int lane = (idx >> 3) & 63;
    int tile = idx >> 9;                      // 0..95
    int kg = lane >> 4, ln = lane & 15;

    if (!isUp) {
        int ks = tile >> 2, nt = tile & 3;
        int k = ks * 32 + kg * 8 + j;         // 0..767 (in-dim of W_down)
        int a = nt * 16 + ln;                 // 0..63
        int i0 = k / 96, i1 = (k / 12) % 8, i2 = k % 12;
        int i3 = a >> 3, i4 = a & 7;
        float w = tt_entry(cs + 0, cs + 40, cs + 240, cs + 540, cs + 740,
                           i0, i1, i2, i3, i4);
        wdFrag[idx] = f2bf(w);
    } else {
        int s = tile / 48, ht = tile % 48;
        int aIn = s * 32 + kg * 8 + j;        // 0..63 (in-dim of W_up)
        int h = ht * 16 + ln;                 // 0..767
        int i0 = aIn >> 3, i1 = aIn & 7;
        int i2 = h / 64, i3 = (h >> 3) & 7, i4 = h & 7;
        float w = tt_entry(cs + 780, cs + 820, cs + 1020, cs + 1320, cs + 1520,
                           i0, i1, i2, i3, i4);
        wuFrag[idx] = f2bf(w);
    }
}

// ---------------------------------------------------------------------------
// Fused adapter kernel. 32 rows/block, 256 threads = 4 waves (2 wm x 2 wn).
// Phase 1: down-GEMM K=768 via mfma_f32_16x16x32_bf16; hs tile stashed bf16
//          in XOR-swizzled LDS for the residual. gelu (exact erf) -> act LDS.
// Phase 2: up-GEMM K=64, 48 column tiles (24 per wn); epilogue adds residual
//          + b_up and stores fp32.
// LDS: 32*768*2 + 32*64*2 = 53248 B -> 3 blocks/CU.
// ---------------------------------------------------------------------------
#define MT 32

__global__ __launch_bounds__(256) void adapter_fused(
    const float* __restrict__ hs,
    const float* __restrict__ b_down,
    const float* __restrict__ b_up,
    const unsigned short* __restrict__ wdFrag,
    const unsigned short* __restrict__ wuFrag,
    float* __restrict__ out)
{
    __shared__ unsigned short hs_lds[MT * 768];   // bf16, swizzled
    __shared__ unsigned short act_lds[MT * 64];   // bf16, swizzled

    const int t    = threadIdx.x;
    const int lane = t & 63;
    const int wid  = t >> 6;       // 0..3
    const int wm   = wid >> 1;     // row band (16 rows each)
    const int wn   = wid & 1;      // column half
    const int ln   = lane & 15;
    const int kg   = lane >> 4;    // 0..3

    const int row0 = blockIdx.x * MT;

    // ---------------- Phase 1: down GEMM ----------------
    const int arow_l = 16 * wm + ln;               // local row for A frags
    const float* hsrow = hs + (size_t)(row0 + arow_l) * 768;

    f32x4 acc1[2];
#pragma unroll
    for (int i = 0; i < 2; ++i) acc1[i] = (f32x4){0.f, 0.f, 0.f, 0.f};

    const unsigned swzA = (unsigned)((arow_l & 7) << 4);

#pragma unroll 4
    for (int ks = 0; ks < 24; ++ks) {
        const int k0 = ks * 32 + kg * 8;
        float4 fa = *(const float4*)(hsrow + k0);
        float4 fb = *(const float4*)(hsrow + k0 + 4);
        bf16x8 afrag;
        afrag[0] = (short)f2bf(fa.x); afrag[1] = (short)f2bf(fa.y);
        afrag[2] = (short)f2bf(fa.z); afrag[3] = (short)f2bf(fa.w);
        afrag[4] = (short)f2bf(fb.x); afrag[5] = (short)f2bf(fb.y);
        afrag[6] = (short)f2bf(fb.z); afrag[7] = (short)f2bf(fb.w);

        if (wn == 0) {  // stash hs tile (bf16) for the residual, swizzled
            unsigned byteoff = ((unsigned)(arow_l * 1536 + k0 * 2)) ^ swzA;
            *(bf16x8*)((char*)hs_lds + byteoff) = afrag;
        }

#pragma unroll
        for (int i = 0; i < 2; ++i) {
            const int nt = 2 * wn + i;
            bf16x8 bfrag = *(const bf16x8*)(wdFrag + (((ks * 4 + nt) * 64) + lane) * 8);
            acc1[i] = __builtin_amdgcn_mfma_f32_16x16x32_bf16(afrag, bfrag, acc1[i], 0, 0, 0);
        }
    }

    // bias + exact gelu -> act_lds (bf16, swizzled)
#pragma unroll
    for (int i = 0; i < 2; ++i) {
        const int nt = 2 * wn + i;
        const int a = nt * 16 + ln;            // D col = lane&15
        const float bd = b_down[a];
#pragma unroll
        for (int r = 0; r < 4; ++r) {
            const int rr = 16 * wm + kg * 4 + r;   // D row = (lane>>4)*4 + r
            float x = acc1[i][r] + bd;
            float g = 0.5f * x * (1.0f + erff(x * 0.70710678118654752f));
            unsigned byteoff = ((unsigned)(rr * 128 + a * 2)) ^ ((unsigned)((rr & 7) << 4));
            *(unsigned short*)((char*)act_lds + byteoff) = f2bf(g);
        }
    }

    __syncthreads();

    // ---------------- Phase 2: up GEMM ----------------
    // A fragments from act_lds: row = 16*wm + (lane&15), k = s*32 + kg*8
    bf16x8 pa[2];
    {
        const int r = 16 * wm + ln;
        const unsigned swz = (unsigned)((r & 7) << 4);
#pragma unroll
        for (int s = 0; s < 2; ++s) {
            unsigned byteoff = ((unsigned)(r * 128 + (s * 64 + kg * 16))) ^ swz;
            pa[s] = *(const bf16x8*)((char*)act_lds + byteoff);
        }
    }

    for (int n2 = 0; n2 < 24; ++n2) {
        const int ht = wn * 24 + n2;           // 0..47
        f32x4 acc = (f32x4){0.f, 0.f, 0.f, 0.f};
#pragma unroll
        for (int s = 0; s < 2; ++s) {
            bf16x8 bfrag = *(const bf16x8*)(wuFrag + (((s * 48 + ht) * 64) + lane) * 8);
            acc = __builtin_amdgcn_mfma_f32_16x16x32_bf16(pa[s], bfrag, acc, 0, 0, 0);
        }
        const int h = ht * 16 + ln;            // D col
        const float bu = b_up[h];
#pragma unroll
        for (int r = 0; r < 4; ++r) {
            const int rr = 16 * wm + kg * 4 + r;   // local row
            unsigned byteoff = ((unsigned)(rr * 1536 + h * 2)) ^ ((unsigned)((rr & 7) << 4));
            float hv = bf2f(*(const unsigned short*)((char*)hs_lds + byteoff));
            out[(size_t)(row0 + rr) * 768 + h] = acc[r] + hv + bu;
        }
    }
}

extern "C" void kernel_launch(void* const* d_in, const int* in_sizes, int n_in,
                              void* d_out, int out_size, void* d_ws, size_t ws_size,
                              hipStream_t stream) {
    // setup_inputs dict order: hidden_states, b_down, b_up, d0,u0,d1,u1,d2,u2,d3,u3,d4,u4
    const float* hs = (const float*)d_in[0];
    const float* bd = (const float*)d_in[1];
    const float* bu = (const float*)d_in[2];
    const float* d0 = (const float*)d_in[3];
    const float* u0 = (const float*)d_in[4];
    const float* d1 = (const float*)d_in[5];
    const float* u1 = (const float*)d_in[6];
    const float* d2 = (const float*)d_in[7];
    const float* u2 = (const float*)d_in[8];
    const float* d3 = (const float*)d_in[9];
    const float* u3 = (const float*)d_in[10];
    const float* d4 = (const float*)d_in[11];
    const float* u4 = (const float*)d_in[12];

    unsigned short* wdFrag = (unsigned short*)d_ws;            // 49152 bf16
    unsigned short* wuFrag = wdFrag + 49152;                   // 49152 bf16

    tt_build_frags<<<384, 256, 0, stream>>>(d0, d1, d2, d3, d4,
                                            u0, u1, u2, u3, u4,
                                            wdFrag, wuFrag);

    const int rows = 16 * 2048;                // 32768
    adapter_fused<<<rows / MT, 256, 0, stream>>>(hs, bd, bu, wdFrag, wuFrag,
                                                 (float*)d_out);
}

// Round 2
// 48.828 us; speedup vs baseline: 1.3454x; 1.3454x over previous
//
#include <hip/hip_runtime.h>

// ---------------------------------------------------------------------------
// TT-adapter fused kernel for MI355X (gfx950)
// out = hs + gelu(hs @ W_down + b_down) @ W_up + b_up
// W_down [768,64], W_up [64,768] reconstructed from rank-5 TT cores.
//
// Kernel 0: build bf16 weights in MFMA-fragment-ready layout in d_ws.
// Kernel 1: fused kernel, 16 rows/block, hs tile staged fp32 into LDS via
//           global_load_lds (pre-swizzled source), 4 waves = 4-way col split.
// ---------------------------------------------------------------------------

typedef __attribute__((ext_vector_type(8))) short bf16x8;
typedef __attribute__((ext_vector_type(4))) float f32x4;

__device__ __forceinline__ unsigned short f2bf(float f) {
    union { float f; unsigned u; } v; v.f = f;
    unsigned r = (v.u + 0x7FFFu + ((v.u >> 16) & 1u)) >> 16;
    return (unsigned short)r;
}

// Staged TT contraction for one matrix entry (cores in LDS).
__device__ __forceinline__ float tt_entry(
    const float* c0, const float* c1, const float* c2,
    const float* c3, const float* c4,
    int i0, int i1, int i2, int i3, int i4)
{
    float v1[5], v2[5], v3[5];
#pragma unroll
    for (int r2 = 0; r2 < 5; ++r2) {
        float s = 0.f;
#pragma unroll
        for (int r1 = 0; r1 < 5; ++r1)
            s += c0[i0 * 5 + r1] * c1[(r1 * 8 + i1) * 5 + r2];
        v1[r2] = s;
    }
#pragma unroll
    for (int r3 = 0; r3 < 5; ++r3) {
        float s = 0.f;
#pragma unroll
        for (int r2 = 0; r2 < 5; ++r2)
            s += v1[r2] * c2[(r2 * 12 + i2) * 5 + r3];
        v2[r3] = s;
    }
#pragma unroll
    for (int r4 = 0; r4 < 5; ++r4) {
        float s = 0.f;
#pragma unroll
        for (int r3 = 0; r3 < 5; ++r3)
            s += v2[r3] * c3[(r3 * 8 + i3) * 5 + r4];
        v3[r4] = s;
    }
    float w = 0.f;
#pragma unroll
    for (int r4 = 0; r4 < 5; ++r4)
        w += v3[r4] * c4[r4 * 8 + i4];
    return w;
}

// WdFrag[((ks*4+nt)*64 + lane)*8 + j] = Wd[ks*32 + (lane>>4)*8 + j][nt*16 + (lane&15)]
// WuFrag[((s*48+ht)*64 + lane)*8 + j] = Wu[s*32  + (lane>>4)*8 + j][ht*16 + (lane&15)]
__global__ __launch_bounds__(256) void tt_build_frags(
    const float* __restrict__ d0, const float* __restrict__ d1,
    const float* __restrict__ d2, const float* __restrict__ d3,
    const float* __restrict__ d4,
    const float* __restrict__ u0, const float* __restrict__ u1,
    const float* __restrict__ u2, const float* __restrict__ u3,
    const float* __restrict__ u4,
    unsigned short* __restrict__ wdFrag, unsigned short* __restrict__ wuFrag)
{
    __shared__ float cs[1560];
    {
        const float* srcs[10] = { d0, d1, d2, d3, d4, u0, u1, u2, u3, u4 };
        const int sizes[10]   = { 40, 200, 300, 200, 40, 40, 200, 300, 200, 40 };
        const int offs[10]    = { 0, 40, 240, 540, 740, 780, 820, 1020, 1320, 1520 };
#pragma unroll
        for (int c = 0; c < 10; ++c)
            for (int i = threadIdx.x; i < sizes[c]; i += 256)
                cs[offs[c] + i] = srcs[c][i];
    }
    __syncthreads();

    int e = blockIdx.x * 256 + threadIdx.x;   // 0..98303
    bool isUp = (e >= 49152);
    int idx = isUp ? (e - 49152) : e;
    int j    = idx & 7;
    int lane = (idx >> 3) & 63;
    int tile = idx >> 9;                      // 0..95
    int kg = lane >> 4, ln = lane & 15;

    if (!isUp) {
        int ks = tile >> 2, nt = tile & 3;
        int k = ks * 32 + kg * 8 + j;
        int a = nt * 16 + ln;
        int i0 = k / 96, i1 = (k / 12) % 8, i2 = k % 12;
        int i3 = a >> 3, i4 = a & 7;
        float w = tt_entry(cs + 0, cs + 40, cs + 240, cs + 540, cs + 740,
                           i0, i1, i2, i3, i4);
        wdFrag[idx] = f2bf(w);
    } else {
        int s = tile / 48, ht = tile % 48;
        int aIn = s * 32 + kg * 8 + j;
        int h = ht * 16 + ln;
        int i0 = aIn >> 3, i1 = aIn & 7;
        int i2 = h / 64, i3 = (h >> 3) & 7, i4 = h & 7;
        float w = tt_entry(cs + 780, cs + 820, cs + 1020, cs + 1320, cs + 1520,
                           i0, i1, i2, i3, i4);
        wuFrag[idx] = f2bf(w);
    }
}

// ---------------------------------------------------------------------------
// Fused adapter kernel. MT=16 rows/block, 2048 blocks, 256 thr = 4 waves.
// Stage: hs tile fp32 -> LDS via global_load_lds (12 x 4KB rounds, all in
//        flight), source pre-swizzled with XOR ((row&7)<<4) so swizzled
//        reads are bank-conflict-free.
// Phase 1: down-GEMM K=768, A from LDS (fp32->bf16), B = wave's 16-col tile.
// Phase 2: up-GEMM K=64, 12 col-tiles/wave; residual read fp32 from LDS.
// LDS 50KB -> 3 blocks/CU.
// ---------------------------------------------------------------------------
#define MT 16

__global__ __launch_bounds__(256) void adapter_fused(
    const float* __restrict__ hs,
    const float* __restrict__ b_down,
    const float* __restrict__ b_up,
    const unsigned short* __restrict__ wdFrag,
    const unsigned short* __restrict__ wuFrag,
    float* __restrict__ out)
{
    __shared__ float hs_s[MT * 768];            // 48KB fp32, XOR-swizzled
    __shared__ unsigned short act_s[MT * 64];   // 2KB bf16, swizzled

    const int t    = threadIdx.x;
    const int lane = t & 63;
    const int w    = t >> 6;       // wave id = column split
    const int ln   = lane & 15;
    const int kg   = lane >> 4;

    const int row0 = blockIdx.x * MT;

    // ---- stage hs tile: 49152 B, 12 rounds x (4 waves x 64 lanes x 16B) ----
    {
        const char* gbase = (const char*)(hs + (size_t)row0 * 768);
#pragma unroll
        for (int i = 0; i < 12; ++i) {
            unsigned d = (unsigned)(i * 4096 + w * 1024 + lane * 16);
            unsigned row = d / 3072u;                       // 0..15
            unsigned src = d ^ ((row & 7u) << 4);           // involution
            __builtin_amdgcn_global_load_lds(
                (const __attribute__((address_space(1))) unsigned int*)(gbase + src),
                (__attribute__((address_space(3))) unsigned int*)
                    ((char*)hs_s + i * 4096 + w * 1024),
                16, 0, 0);
        }
    }
    __syncthreads();

    // ---------------- Phase 1: down GEMM (K = 768) ----------------
    const unsigned swzA = (unsigned)((ln & 7) << 4);
    f32x4 acc1 = (f32x4){0.f, 0.f, 0.f, 0.f};

#pragma unroll 8
    for (int ks = 0; ks < 24; ++ks) {
        unsigned a0 = ((unsigned)(ln * 3072 + ks * 128 + kg * 32)) ^ swzA;
        f32x4 fa = *(const f32x4*)((const char*)hs_s + a0);
        f32x4 fb = *(const f32x4*)((const char*)hs_s + (a0 ^ 16u));
        bf16x8 afrag;
        afrag[0] = (short)f2bf(fa[0]); afrag[1] = (short)f2bf(fa[1]);
        afrag[2] = (short)f2bf(fa[2]); afrag[3] = (short)f2bf(fa[3]);
        afrag[4] = (short)f2bf(fb[0]); afrag[5] = (short)f2bf(fb[1]);
        afrag[6] = (short)f2bf(fb[2]); afrag[7] = (short)f2bf(fb[3]);
        bf16x8 bfrag = *(const bf16x8*)(wdFrag + (((ks * 4 + w) * 64) + lane) * 8);
        acc1 = __builtin_amdgcn_mfma_f32_16x16x32_bf16(afrag, bfrag, acc1, 0, 0, 0);
    }

    // bias + exact gelu -> act_s (bf16, swizzled)
    {
        const int a = w * 16 + ln;              // D col
        const float bd = b_down[a];
#pragma unroll
        for (int r = 0; r < 4; ++r) {
            const int rr = kg * 4 + r;          // D row
            float x = acc1[r] + bd;
            float g = 0.5f * x * (1.0f + erff(x * 0.70710678118654752f));
            unsigned off = ((unsigned)(rr * 128 + a * 2)) ^ ((unsigned)((rr & 7) << 4));
            *(unsigned short*)((char*)act_s + off) = f2bf(g);
        }
    }
    __syncthreads();

    // ---------------- Phase 2: up GEMM (K = 64) ----------------
    bf16x8 pa[2];
    {
        const unsigned swz = (unsigned)((ln & 7) << 4);
#pragma unroll
        for (int s = 0; s < 2; ++s) {
            unsigned off = ((unsigned)(ln * 128 + s * 64 + kg * 16)) ^ swz;
            pa[s] = *(const bf16x8*)((const char*)act_s + off);
        }
    }

#pragma unroll 4
    for (int n2 = 0; n2 < 12; ++n2) {
        const int ht = w * 12 + n2;             // 0..47
        f32x4 acc = (f32x4){0.f, 0.f, 0.f, 0.f};
#pragma unroll
        for (int s = 0; s < 2; ++s) {
            bf16x8 bfrag = *(const bf16x8*)(wuFrag + (((s * 48 + ht) * 64) + lane) * 8);
            acc = __builtin_amdgcn_mfma_f32_16x16x32_bf16(pa[s], bfrag, acc, 0, 0, 0);
        }
        const int h = ht * 16 + ln;             // D col
        const float bu = b_up[h];
#pragma unroll
        for (int r = 0; r < 4; ++r) {
            const int rr = kg * 4 + r;          // D row (local)
            unsigned off = ((unsigned)(rr * 3072 + h * 4)) ^ ((unsigned)((rr & 7) << 4));
            float hv = *(const float*)((const char*)hs_s + off);
            out[(size_t)(row0 + rr) * 768 + h] = acc[r] + hv + bu;
        }
    }
}

extern "C" void kernel_launch(void* const* d_in, const int* in_sizes, int n_in,
                              void* d_out, int out_size, void* d_ws, size_t ws_size,
                              hipStream_t stream) {
    // dict order: hidden_states, b_down, b_up, d0,u0,d1,u1,d2,u2,d3,u3,d4,u4
    const float* hs = (const float*)d_in[0];
    const float* bd = (const float*)d_in[1];
    const float* bu = (const float*)d_in[2];
    const float* d0 = (const float*)d_in[3];
    const float* u0 = (const float*)d_in[4];
    const float* d1 = (const float*)d_in[5];
    const float* u1 = (const float*)d_in[6];
    const float* d2 = (const float*)d_in[7];
    const float* u2 = (const float*)d_in[8];
    const float* d3 = (const float*)d_in[9];
    const float* u3 = (const float*)d_in[10];
    const float* d4 = (const float*)d_in[11];
    const float* u4 = (const float*)d_in[12];

    unsigned short* wdFrag = (unsigned short*)d_ws;            // 49152 bf16
    unsigned short* wuFrag = wdFrag + 49152;                   // 49152 bf16

    tt_build_frags<<<384, 256, 0, stream>>>(d0, d1, d2, d3, d4,
                                            u0, u1, u2, u3, u4,
                                            wdFrag, wuFrag);

    const int rows = 16 * 2048;                // 32768 rows
    adapter_fused<<<rows / MT, 256, 0, stream>>>(hs, bd, bu, wdFrag, wuFrag,
                                                 (float*)d_out);
}